// Round 8
// baseline (414.303 us; speedup 1.0000x reference)
//
#include <hip/hip_runtime.h>

#define EPS 1e-5f
#define NTHR 256
#define NBLK 512
#define NSLOT 16
#define TPW 32   // tiles per wave: 2097152/32 rows/tile / (512*4 waves) = 32 exact

typedef __bf16 bf16x8 __attribute__((ext_vector_type(8)));
typedef float f32x16 __attribute__((ext_vector_type(16)));

// d_ws layout:
//   [0, 3*NSLOT*64*4)  stats slots: layer L: stats[L*NSLOT*64 + slot*64 + idx]
//                      idx 0..31 = sum(z_L), 32..63 = sum(z_L^2)
//   [.., +64)          grid barrier {count, generation}
//
// Layout algebra (m74/m101-verified 32x32x16 mappings):
//   C/D: col=lane&31 (data row), row p = (reg&3)+8*(reg>>2)+4h, h=lane>>5
//   A:   m=lane&31, k=8h+j ;  B: n=lane&31, k=8h+j
// Acc regs 0..7 / 8..15 feed the next layer's B-frag; next weights use columns
// permuted by phi(K)=(j&3)+8*(j>>2)+4h+16*kh (involution). BN scale a>0 folds
// into next-layer weight columns; shift e folds into the MFMA accumulator init.
//
// R8: x-in-registers persistent kernel. 8 rounds showed the 4-pass structure
// is schedule-insensitive (~135us kernels, all pipes idle); the remaining big
// term is structural: x re-read 4x + 3 kernel cold-starts. Fix: each wave
// holds its whole 32-tile x-chunk in 128 VGPR of bf16 across all 4 phases.
// x is read ONCE (128 MiB); phases 2-4 are pure-register compute; xb is gone
// (saves 64 MiB write + 192 MiB reads). VGPR budget ~230 <= 256 cap from
// __launch_bounds__(256,2) — cap guarantees 2 blocks/CU co-residency for the
// grid barrier even if the compiler spills (slow-but-correct failure mode).
// All xr[] indexing is static (full unroll; rule-#20). Barrier machinery
// verbatim from R3 (correctness-verified).

__global__ __launch_bounds__(NTHR, 2) void k_all(
    const float* __restrict__ x,
    const float* __restrict__ W1, const float* __restrict__ b1,
    const float* __restrict__ g1, const float* __restrict__ be1,
    const float* __restrict__ W2, const float* __restrict__ b2,
    const float* __restrict__ g2, const float* __restrict__ be2,
    const float* __restrict__ W3, const float* __restrict__ b3,
    const float* __restrict__ g3, const float* __restrict__ be3,
    const float* __restrict__ W4, const float* __restrict__ b4,
    float* __restrict__ stats, unsigned* __restrict__ bar,
    float* __restrict__ out, int N)
{
    __shared__ float s_stat[64];
    __shared__ float s_a[32];
    __shared__ float s_e[32];
    __shared__ float s_w[NTHR / 64][64];

    const int tid = threadIdx.x;
    const int lane = tid & 63;
    const int h = lane >> 5;
    const int ml = lane & 31;
    const float invN = 1.0f / (float)N;

    const int ntiles = N >> 5;
    const int nwaves = NBLK * (NTHR / 64);
    const int gwave  = blockIdx.x * (NTHR / 64) + (tid >> 6);
    const int tpw    = ntiles / nwaves;
    const int rem    = ntiles - tpw * nwaves;
    const int t0     = gwave * tpw + (gwave < rem ? gwave : rem);
    const int cnt    = tpw + (gwave < rem ? 1 : 0);   // == 32 for this shape

    // ---- device-scope grid barrier (verbatim R3, verified) ----
    auto gbar = [&](unsigned target) {
        __syncthreads();
        if (tid == 0) {
            __threadfence();
            unsigned old = __hip_atomic_fetch_add(&bar[0], 1u, __ATOMIC_ACQ_REL, __HIP_MEMORY_SCOPE_AGENT);
            if (old == (unsigned)(NBLK - 1)) {
                __hip_atomic_store(&bar[0], 0u, __ATOMIC_RELAXED, __HIP_MEMORY_SCOPE_AGENT);
                __hip_atomic_fetch_add(&bar[1], 1u, __ATOMIC_RELEASE, __HIP_MEMORY_SCOPE_AGENT);
            } else {
                while (__hip_atomic_load(&bar[1], __ATOMIC_ACQUIRE, __HIP_MEMORY_SCOPE_AGENT) < target)
                    __builtin_amdgcn_s_sleep(2);
            }
        }
        __syncthreads();
    };

    auto derive = [&](int L, const float* g, const float* be, const float* b) {
        if (tid < 64) {
            float a = 0.f;
            #pragma unroll
            for (int s = 0; s < NSLOT; ++s)
                a += __hip_atomic_load(&stats[L * (NSLOT * 64) + s * 64 + tid],
                                       __ATOMIC_RELAXED, __HIP_MEMORY_SCOPE_AGENT);
            s_stat[tid] = a;
        }
        __syncthreads();
        if (tid < 32) {
            float mu = s_stat[tid] * invN;
            float v  = s_stat[32 + tid] * invN - mu * mu;
            float a  = g[tid] * rsqrtf(v + EPS);
            s_a[tid] = a;
            s_e[tid] = b[tid] - mu + be[tid] / a;
        }
        __syncthreads();
    };

    float sums[16], sqs[16];

    auto flush_stats = [&](int L) {
        const int wid = tid >> 6;
        #pragma unroll
        for (int i = 0; i < 16; ++i) {
            float s = sums[i], q = sqs[i];
            #pragma unroll
            for (int d = 1; d <= 16; d <<= 1) {
                s += __shfl_xor(s, d);
                q += __shfl_xor(q, d);
            }
            if (ml == 0) {
                int p = (i & 3) + 8 * (i >> 2) + 4 * h;
                s_w[wid][p] = s;
                s_w[wid][32 + p] = q;
            }
        }
        __syncthreads();
        if (tid < 64) {
            float a = s_w[0][tid] + s_w[1][tid] + s_w[2][tid] + s_w[3][tid];
            atomicAdd(&stats[L * (NSLOT * 64) + (blockIdx.x & (NSLOT - 1)) * 64 + tid], a);
        }
    };

    // ---- persistent fragments ----
    bf16x8 w1f;
    {
        const float* p = W1 + ml * 16 + h * 8;
        #pragma unroll
        for (int j = 0; j < 8; ++j) w1f[j] = (__bf16)p[j];
    }
    f32x16 c1;
    #pragma unroll
    for (int i = 0; i < 16; ++i) {
        int p = (i & 3) + 8 * (i >> 2) + 4 * h;
        c1[i] = b1[p];
    }

    // the wave's x-chunk, held in registers across all phases (static idx only)
    bf16x8 xr[TPW];

    // ================= phase 1: load x once, stats of z1 =================
    #pragma unroll
    for (int i = 0; i < 16; ++i) { sums[i] = 0.f; sqs[i] = 0.f; }
    #pragma unroll
    for (int b = 0; b < TPW / 4; ++b) {
        float4 u0[4], u1[4];
        #pragma unroll
        for (int k = 0; k < 4; ++k) {
            int i = b * 4 + k;
            if (i < cnt) {
                const float4* p = (const float4*)(x + (size_t)(((t0 + i) << 5) + ml) * 16 + h * 8);
                u0[k] = p[0]; u1[k] = p[1];
            }
        }
        #pragma unroll
        for (int k = 0; k < 4; ++k) {
            int i = b * 4 + k;
            if (i < cnt) {
                bf16x8 xf;
                xf[0] = (__bf16)u0[k].x; xf[1] = (__bf16)u0[k].y;
                xf[2] = (__bf16)u0[k].z; xf[3] = (__bf16)u0[k].w;
                xf[4] = (__bf16)u1[k].x; xf[5] = (__bf16)u1[k].y;
                xf[6] = (__bf16)u1[k].z; xf[7] = (__bf16)u1[k].w;
                xr[i] = xf;
                f32x16 a1 = __builtin_amdgcn_mfma_f32_32x32x16_bf16(w1f, xf, c1, 0, 0, 0);
                #pragma unroll
                for (int q = 0; q < 16; ++q) { sums[q] += a1[q]; sqs[q] = fmaf(a1[q], a1[q], sqs[q]); }
            } else {
                bf16x8 z = {};
                xr[i] = z;
            }
        }
    }
    flush_stats(0);
    gbar(1);

    // ================= phase 2: stats of z2 (pure-register) =================
    derive(0, g1, be1, b1);
    #pragma unroll
    for (int i = 0; i < 16; ++i) {
        int p = (i & 3) + 8 * (i >> 2) + 4 * h;
        c1[i] = s_e[p];
    }
    bf16x8 w2f0, w2f1;
    #pragma unroll
    for (int kh = 0; kh < 2; ++kh)
        #pragma unroll
        for (int j = 0; j < 8; ++j) {
            int pk = (j & 3) + 8 * (j >> 2) + 4 * h + 16 * kh;
            float v = W2[ml * 32 + pk] * s_a[pk];
            if (kh == 0) w2f0[j] = (__bf16)v; else w2f1[j] = (__bf16)v;
        }
    f32x16 c2;
    #pragma unroll
    for (int i = 0; i < 16; ++i) {
        int p = (i & 3) + 8 * (i >> 2) + 4 * h;
        c2[i] = b2[p];
    }
    #pragma unroll
    for (int i = 0; i < 16; ++i) { sums[i] = 0.f; sqs[i] = 0.f; }
    #pragma unroll
    for (int i = 0; i < TPW; ++i) {
        if (i < cnt) {
            f32x16 a1 = __builtin_amdgcn_mfma_f32_32x32x16_bf16(w1f, xr[i], c1, 0, 0, 0);
            bf16x8 qa, qb;
            #pragma unroll
            for (int j = 0; j < 8; ++j) {
                qa[j] = (__bf16)fmaxf(a1[j], 0.f);
                qb[j] = (__bf16)fmaxf(a1[8 + j], 0.f);
            }
            f32x16 a2 = __builtin_amdgcn_mfma_f32_32x32x16_bf16(w2f0, qa, c2, 0, 0, 0);
            a2 = __builtin_amdgcn_mfma_f32_32x32x16_bf16(w2f1, qb, a2, 0, 0, 0);
            #pragma unroll
            for (int q = 0; q < 16; ++q) { sums[q] += a2[q]; sqs[q] = fmaf(a2[q], a2[q], sqs[q]); }
        }
    }
    flush_stats(1);
    gbar(2);

    // ================= phase 3: stats of z3 (pure-register) =================
    derive(1, g2, be2, b2);
    #pragma unroll
    for (int i = 0; i < 16; ++i) {
        int p = (i & 3) + 8 * (i >> 2) + 4 * h;
        c2[i] = s_e[p];
    }
    bf16x8 w3f0, w3f1;
    #pragma unroll
    for (int kh = 0; kh < 2; ++kh)
        #pragma unroll
        for (int j = 0; j < 8; ++j) {
            int pk = (j & 3) + 8 * (j >> 2) + 4 * h + 16 * kh;
            float v = W3[ml * 32 + pk] * s_a[pk];
            if (kh == 0) w3f0[j] = (__bf16)v; else w3f1[j] = (__bf16)v;
        }
    f32x16 c3;
    #pragma unroll
    for (int i = 0; i < 16; ++i) {
        int p = (i & 3) + 8 * (i >> 2) + 4 * h;
        c3[i] = b3[p];
    }
    #pragma unroll
    for (int i = 0; i < 16; ++i) { sums[i] = 0.f; sqs[i] = 0.f; }
    #pragma unroll
    for (int i = 0; i < TPW; ++i) {
        if (i < cnt) {
            f32x16 a1 = __builtin_amdgcn_mfma_f32_32x32x16_bf16(w1f, xr[i], c1, 0, 0, 0);
            bf16x8 qa, qb;
            #pragma unroll
            for (int j = 0; j < 8; ++j) {
                qa[j] = (__bf16)fmaxf(a1[j], 0.f);
                qb[j] = (__bf16)fmaxf(a1[8 + j], 0.f);
            }
            f32x16 a2 = __builtin_amdgcn_mfma_f32_32x32x16_bf16(w2f0, qa, c2, 0, 0, 0);
            a2 = __builtin_amdgcn_mfma_f32_32x32x16_bf16(w2f1, qb, a2, 0, 0, 0);
            bf16x8 pa, pb;
            #pragma unroll
            for (int j = 0; j < 8; ++j) {
                pa[j] = (__bf16)fmaxf(a2[j], 0.f);
                pb[j] = (__bf16)fmaxf(a2[8 + j], 0.f);
            }
            f32x16 a3 = __builtin_amdgcn_mfma_f32_32x32x16_bf16(w3f0, pa, c3, 0, 0, 0);
            a3 = __builtin_amdgcn_mfma_f32_32x32x16_bf16(w3f1, pb, a3, 0, 0, 0);
            #pragma unroll
            for (int q = 0; q < 16; ++q) { sums[q] += a3[q]; sqs[q] = fmaf(a3[q], a3[q], sqs[q]); }
        }
    }
    flush_stats(2);
    gbar(3);

    // ================= phase 4: output (pure-register + 8 MiB store) =======
    derive(2, g3, be3, b3);
    #pragma unroll
    for (int i = 0; i < 16; ++i) {
        int p = (i & 3) + 8 * (i >> 2) + 4 * h;
        c3[i] = s_e[p];
    }
    float w4c[16];
    #pragma unroll
    for (int i = 0; i < 16; ++i) {
        int p = (i & 3) + 8 * (i >> 2) + 4 * h;
        w4c[i] = W4[p] * s_a[p];
    }
    const float b4v = b4[0];
    #pragma unroll
    for (int i = 0; i < TPW; ++i) {
        if (i < cnt) {
            f32x16 a1 = __builtin_amdgcn_mfma_f32_32x32x16_bf16(w1f, xr[i], c1, 0, 0, 0);
            bf16x8 qa, qb;
            #pragma unroll
            for (int j = 0; j < 8; ++j) {
                qa[j] = (__bf16)fmaxf(a1[j], 0.f);
                qb[j] = (__bf16)fmaxf(a1[8 + j], 0.f);
            }
            f32x16 a2 = __builtin_amdgcn_mfma_f32_32x32x16_bf16(w2f0, qa, c2, 0, 0, 0);
            a2 = __builtin_amdgcn_mfma_f32_32x32x16_bf16(w2f1, qb, a2, 0, 0, 0);
            bf16x8 pa, pb;
            #pragma unroll
            for (int j = 0; j < 8; ++j) {
                pa[j] = (__bf16)fmaxf(a2[j], 0.f);
                pb[j] = (__bf16)fmaxf(a2[8 + j], 0.f);
            }
            f32x16 a3 = __builtin_amdgcn_mfma_f32_32x32x16_bf16(w3f0, pa, c3, 0, 0, 0);
            a3 = __builtin_amdgcn_mfma_f32_32x32x16_bf16(w3f1, pb, a3, 0, 0, 0);
            float o = 0.f;
            #pragma unroll
            for (int q = 0; q < 16; ++q) o = fmaf(w4c[q], fmaxf(a3[q], 0.f), o);
            o += __shfl_xor(o, 32);
            if (h == 0) out[((t0 + i) << 5) + ml] = o + b4v;
        }
    }
}

extern "C" void kernel_launch(void* const* d_in, const int* in_sizes, int n_in,
                              void* d_out, int out_size, void* d_ws, size_t ws_size,
                              hipStream_t stream) {
    const float* x   = (const float*)d_in[0];
    const float* W1  = (const float*)d_in[1];
    const float* b1  = (const float*)d_in[2];
    const float* g1  = (const float*)d_in[3];
    const float* be1 = (const float*)d_in[4];
    const float* W2  = (const float*)d_in[5];
    const float* b2  = (const float*)d_in[6];
    const float* g2  = (const float*)d_in[7];
    const float* be2 = (const float*)d_in[8];
    const float* W3  = (const float*)d_in[9];
    const float* b3  = (const float*)d_in[10];
    const float* g3  = (const float*)d_in[11];
    const float* be3 = (const float*)d_in[12];
    const float* W4  = (const float*)d_in[13];
    const float* b4  = (const float*)d_in[14];
    float* out = (float*)d_out;
    int N = in_sizes[0] / 16;

    float* stats  = (float*)d_ws;
    unsigned* bar = (unsigned*)((char*)d_ws + 3 * NSLOT * 64 * sizeof(float));

    // zero stats slots + barrier {count, gen}
    hipMemsetAsync(stats, 0, 3 * NSLOT * 64 * sizeof(float) + 64, stream);

    k_all<<<NBLK, NTHR, 0, stream>>>(x, W1, b1, g1, be1, W2, b2, g2, be2,
                                     W3, b3, g3, be3, W4, b4, stats, bar, out, N);
}

// Round 9
// 326.784 us; speedup vs baseline: 1.2678x; 1.2678x over previous
//
#include <hip/hip_runtime.h>

#define EPS 1e-5f
#define NTHR 256
#define NBLK 1024
#define NSLOT 16

typedef __bf16 bf16x8 __attribute__((ext_vector_type(8)));
typedef float f32x16 __attribute__((ext_vector_type(16)));

// d_ws layout:
//   [0, N*16*2)              bf16 copy of x, tile-major in MFMA B-frag order:
//                            xb[(t*64 + lane)*8 .. +8) = 8 bf16 for (tile t, lane)
//   [N*16*2, +3*NSLOT*64*4)  stats slots: layer L: stats[L*NSLOT*64 + slot*64 + idx]
//                            idx 0..31 = sum(z_L), 32..63 = sum(z_L^2)
//
// Layout algebra (m74/m101-verified 32x32x16 mappings):
//   C/D: col=lane&31 (data row), row p = (reg&3)+8*(reg>>2)+4h, h=lane>>5
//   A:   m=lane&31, k=8h+j ;  B: n=lane&31, k=8h+j
// Acc regs 0..7 / 8..15 feed the next layer's B-frag; next weights use columns
// permuted by phi(K)=(j&3)+8*(j>>2)+4h+16*kh (involution). BN scale a>0 folds
// into next-layer weight columns; shift e folds into the MFMA accumulator init.
//
// R9: ILP restructure. R8 proved the passes are pure dependency-latency bound
// (zero-memory phases ran at identical speed; MfmaUtil 4.4% == exact useful
// MFMA work at ~10% duty cycle), and TLP is VGPR-capped at 16 waves/CU (R7's
// NBLK=2048 added zero resident waves). Only lever left: ILP. This round:
// batch-of-4 LAYER-MAJOR execution — all 4 tiles' L1 MFMAs issued
// back-to-back, then all cvt blocks, then all L2 MFMAs, ... so 4 independent
// chains overlap in one wave. Peak live regs ~210 < 256 (a-accs of the batch
// = 64 VGPR live at once vs 4 full chains' ~160 in tile-major order).
// Everything else identical to R6 (best: 314.9us).

template<int DEPTH>
__global__ __launch_bounds__(NTHR) void k_fwd(
    const float* __restrict__ x, __bf16* __restrict__ xb,
    const float* __restrict__ W1, const float* __restrict__ b1,
    const float* __restrict__ g1, const float* __restrict__ be1,
    const float* __restrict__ W2, const float* __restrict__ b2,
    const float* __restrict__ g2, const float* __restrict__ be2,
    const float* __restrict__ W3, const float* __restrict__ b3,
    const float* __restrict__ g3, const float* __restrict__ be3,
    const float* __restrict__ W4, const float* __restrict__ b4,
    float* __restrict__ stats, float* __restrict__ out, int N)
{
    constexpr bool STATS = (DEPTH < 4);
    __shared__ float s_stat[3][64];
    __shared__ float s_a[3][32];
    __shared__ float s_e[3][32];
    __shared__ float s_w[NTHR / 64][64];

    const int tid = threadIdx.x;
    const float invN = 1.0f / (float)N;

    // Phase A: combine slot partials for layers whose stats are known
    if (tid < 64) {
        #pragma unroll
        for (int L = 0; L < DEPTH - 1; ++L) {
            float a = 0.f;
            #pragma unroll
            for (int s = 0; s < NSLOT; ++s) a += stats[L * (NSLOT * 64) + s * 64 + tid];
            s_stat[L][tid] = a;
        }
    }
    __syncthreads();
    // Phase B: derive BN scale a and additive fold e per feature
    if (tid < 32) {
        const float* gs[3]  = {g1, g2, g3};
        const float* bes[3] = {be1, be2, be3};
        const float* bs[3]  = {b1, b2, b3};
        #pragma unroll
        for (int L = 0; L < DEPTH - 1; ++L) {
            float mu = s_stat[L][tid] * invN;
            float v  = s_stat[L][32 + tid] * invN - mu * mu;
            float a  = gs[L][tid] * rsqrtf(v + EPS);
            s_a[L][tid] = a;
            s_e[L][tid] = bs[L][tid] - mu + bes[L][tid] / a;
        }
    }
    __syncthreads();

    // Phase C: per-thread fragments and constants
    const int lane = tid & 63;
    const int h = lane >> 5;
    const int ml = lane & 31;

    bf16x8 w1f;
    {
        const float* p = W1 + ml * 16 + h * 8;
        #pragma unroll
        for (int j = 0; j < 8; ++j) w1f[j] = (__bf16)p[j];
    }
    bf16x8 w2f0 = {}, w2f1 = {}, w3f0 = {}, w3f1 = {};
    if (DEPTH >= 2) {
        #pragma unroll
        for (int kh = 0; kh < 2; ++kh)
            #pragma unroll
            for (int j = 0; j < 8; ++j) {
                int pk = (j & 3) + 8 * (j >> 2) + 4 * h + 16 * kh;
                float v = W2[ml * 32 + pk] * s_a[0][pk];
                if (kh == 0) w2f0[j] = (__bf16)v; else w2f1[j] = (__bf16)v;
            }
    }
    if (DEPTH >= 3) {
        #pragma unroll
        for (int kh = 0; kh < 2; ++kh)
            #pragma unroll
            for (int j = 0; j < 8; ++j) {
                int pk = (j & 3) + 8 * (j >> 2) + 4 * h + 16 * kh;
                float v = W3[ml * 32 + pk] * s_a[1][pk];
                if (kh == 0) w3f0[j] = (__bf16)v; else w3f1[j] = (__bf16)v;
            }
    }

    f32x16 c1, c2 = {}, c3 = {};
    float w4c[16];
    #pragma unroll
    for (int i = 0; i < 16; ++i) {
        int p = (i & 3) + 8 * (i >> 2) + 4 * h;
        c1[i] = (DEPTH == 1) ? b1[p] : s_e[0][p];
        if (DEPTH >= 2) c2[i] = (DEPTH == 2) ? b2[p] : s_e[1][p];
        if (DEPTH >= 3) c3[i] = (DEPTH == 3) ? b3[p] : s_e[2][p];
        if (DEPTH == 4) w4c[i] = W4[p] * s_a[2][p]; else w4c[i] = 0.f;
    }
    const float b4v = (DEPTH == 4) ? b4[0] : 0.f;

    // exact contiguous split: wave owns tiles [t0, t0+cnt)
    const int ntiles = N >> 5;
    const int nwaves = NBLK * (NTHR / 64);
    const int gwave  = blockIdx.x * (NTHR / 64) + (tid >> 6);
    const int tpw    = ntiles / nwaves;
    const int rem    = ntiles - tpw * nwaves;
    const int t0     = gwave * tpw + (gwave < rem ? gwave : rem);
    const int cnt    = tpw + (gwave < rem ? 1 : 0);

    float sums[16], sqs[16];
    #pragma unroll
    for (int i = 0; i < 16; ++i) { sums[i] = 0.f; sqs[i] = 0.f; }

    auto cvt = [&](float4 a, float4 b) -> bf16x8 {
        bf16x8 xf;
        xf[0] = (__bf16)a.x; xf[1] = (__bf16)a.y; xf[2] = (__bf16)a.z; xf[3] = (__bf16)a.w;
        xf[4] = (__bf16)b.x; xf[5] = (__bf16)b.y; xf[6] = (__bf16)b.z; xf[7] = (__bf16)b.w;
        return xf;
    };

    // layer-major batch of 4 tiles: 4 independent MFMA chains overlapped
    auto batch4 = [&](int tb, const bf16x8* xf) {
        f32x16 A[4];
        // L1: 4 independent MFMAs
        #pragma unroll
        for (int k = 0; k < 4; ++k)
            A[k] = __builtin_amdgcn_mfma_f32_32x32x16_bf16(w1f, xf[k], c1, 0, 0, 0);
        if (DEPTH == 1) {
            #pragma unroll
            for (int k = 0; k < 4; ++k)
                #pragma unroll
                for (int q = 0; q < 16; ++q) { sums[q] += A[k][q]; sqs[q] = fmaf(A[k][q], A[k][q], sqs[q]); }
            return;
        }
        // ReLU+cvt for all 4, then L2 MFMAs for all 4
        bf16x8 qa[4], qb[4];
        #pragma unroll
        for (int k = 0; k < 4; ++k)
            #pragma unroll
            for (int j = 0; j < 8; ++j) {
                qa[k][j] = (__bf16)fmaxf(A[k][j], 0.f);
                qb[k][j] = (__bf16)fmaxf(A[k][8 + j], 0.f);
            }
        #pragma unroll
        for (int k = 0; k < 4; ++k)
            A[k] = __builtin_amdgcn_mfma_f32_32x32x16_bf16(w2f0, qa[k], c2, 0, 0, 0);
        #pragma unroll
        for (int k = 0; k < 4; ++k)
            A[k] = __builtin_amdgcn_mfma_f32_32x32x16_bf16(w2f1, qb[k], A[k], 0, 0, 0);
        if (DEPTH == 2) {
            #pragma unroll
            for (int k = 0; k < 4; ++k)
                #pragma unroll
                for (int q = 0; q < 16; ++q) { sums[q] += A[k][q]; sqs[q] = fmaf(A[k][q], A[k][q], sqs[q]); }
            return;
        }
        #pragma unroll
        for (int k = 0; k < 4; ++k)
            #pragma unroll
            for (int j = 0; j < 8; ++j) {
                qa[k][j] = (__bf16)fmaxf(A[k][j], 0.f);
                qb[k][j] = (__bf16)fmaxf(A[k][8 + j], 0.f);
            }
        #pragma unroll
        for (int k = 0; k < 4; ++k)
            A[k] = __builtin_amdgcn_mfma_f32_32x32x16_bf16(w3f0, qa[k], c3, 0, 0, 0);
        #pragma unroll
        for (int k = 0; k < 4; ++k)
            A[k] = __builtin_amdgcn_mfma_f32_32x32x16_bf16(w3f1, qb[k], A[k], 0, 0, 0);
        if (DEPTH == 3) {
            #pragma unroll
            for (int k = 0; k < 4; ++k)
                #pragma unroll
                for (int q = 0; q < 16; ++q) { sums[q] += A[k][q]; sqs[q] = fmaf(A[k][q], A[k][q], sqs[q]); }
            return;
        }
        #pragma unroll
        for (int k = 0; k < 4; ++k) {
            float o = 0.f;
            #pragma unroll
            for (int q = 0; q < 16; ++q) o = fmaf(w4c[q], fmaxf(A[k][q], 0.f), o);
            o += __shfl_xor(o, 32);
            if (h == 0) out[((tb + k) << 5) + ml] = o + b4v;
        }
    };

    // single-tile path for the (normally empty) remainder
    auto tile1 = [&](int t, bf16x8 xf) {
        bf16x8 xa[4] = {xf, xf, xf, xf};
        // reuse batch4 would quadruple stats; do it straight:
        f32x16 a1 = __builtin_amdgcn_mfma_f32_32x32x16_bf16(w1f, xf, c1, 0, 0, 0);
        if (DEPTH == 1) {
            #pragma unroll
            for (int q = 0; q < 16; ++q) { sums[q] += a1[q]; sqs[q] = fmaf(a1[q], a1[q], sqs[q]); }
            return;
        }
        bf16x8 qa, qb;
        #pragma unroll
        for (int j = 0; j < 8; ++j) {
            qa[j] = (__bf16)fmaxf(a1[j], 0.f);
            qb[j] = (__bf16)fmaxf(a1[8 + j], 0.f);
        }
        f32x16 a2 = __builtin_amdgcn_mfma_f32_32x32x16_bf16(w2f0, qa, c2, 0, 0, 0);
        a2 = __builtin_amdgcn_mfma_f32_32x32x16_bf16(w2f1, qb, a2, 0, 0, 0);
        if (DEPTH == 2) {
            #pragma unroll
            for (int q = 0; q < 16; ++q) { sums[q] += a2[q]; sqs[q] = fmaf(a2[q], a2[q], sqs[q]); }
            return;
        }
        #pragma unroll
        for (int j = 0; j < 8; ++j) {
            qa[j] = (__bf16)fmaxf(a2[j], 0.f);
            qb[j] = (__bf16)fmaxf(a2[8 + j], 0.f);
        }
        f32x16 a3 = __builtin_amdgcn_mfma_f32_32x32x16_bf16(w3f0, qa, c3, 0, 0, 0);
        a3 = __builtin_amdgcn_mfma_f32_32x32x16_bf16(w3f1, qb, a3, 0, 0, 0);
        if (DEPTH == 3) {
            #pragma unroll
            for (int q = 0; q < 16; ++q) { sums[q] += a3[q]; sqs[q] = fmaf(a3[q], a3[q], sqs[q]); }
            return;
        }
        float o = 0.f;
        #pragma unroll
        for (int q = 0; q < 16; ++q) o = fmaf(w4c[q], fmaxf(a3[q], 0.f), o);
        o += __shfl_xor(o, 32);
        if (h == 0) out[(t << 5) + ml] = o + b4v;
        (void)xa;
    };

    const int nb4 = cnt & ~3;
    if (DEPTH == 1) {
        for (int i0 = 0; i0 < nb4; i0 += 4) {
            // loads (8 in flight), then cvt x4, then stores x4, then L1 MFMAs x4
            float4 u0[4], u1[4];
            #pragma unroll
            for (int k = 0; k < 4; ++k) {
                const float4* p = (const float4*)(x + (size_t)(((t0 + i0 + k) << 5) + ml) * 16 + h * 8);
                u0[k] = p[0]; u1[k] = p[1];
            }
            bf16x8 xf[4];
            #pragma unroll
            for (int k = 0; k < 4; ++k) xf[k] = cvt(u0[k], u1[k]);
            __bf16* w = xb + ((size_t)(t0 + i0) * 64 + lane) * 8;
            #pragma unroll
            for (int k = 0; k < 4; ++k) *(bf16x8*)(w + k * 512) = xf[k];
            batch4(t0 + i0, xf);
        }
        for (int i = nb4; i < cnt; ++i) {
            const float4* p = (const float4*)(x + (size_t)(((t0 + i) << 5) + ml) * 16 + h * 8);
            bf16x8 xf = cvt(p[0], p[1]);
            *(bf16x8*)(xb + ((size_t)(t0 + i) * 64 + lane) * 8) = xf;
            tile1(t0 + i, xf);
        }
    } else {
        for (int i0 = 0; i0 < nb4; i0 += 4) {
            const __bf16* r = xb + ((size_t)(t0 + i0) * 64 + lane) * 8;
            bf16x8 xf[4];
            #pragma unroll
            for (int k = 0; k < 4; ++k) xf[k] = *(const bf16x8*)(r + (size_t)k * 512);
            batch4(t0 + i0, xf);
        }
        for (int i = nb4; i < cnt; ++i) {
            bf16x8 xf = *(const bf16x8*)(xb + ((size_t)(t0 + i) * 64 + lane) * 8);
            tile1(t0 + i, xf);
        }
    }

    if (STATS) {
        const int wid = tid >> 6;
        #pragma unroll
        for (int i = 0; i < 16; ++i) {
            float s = sums[i], q = sqs[i];
            #pragma unroll
            for (int d = 1; d <= 16; d <<= 1) {
                s += __shfl_xor(s, d);
                q += __shfl_xor(q, d);
            }
            if (ml == 0) {
                int p = (i & 3) + 8 * (i >> 2) + 4 * h;
                s_w[wid][p] = s;
                s_w[wid][32 + p] = q;
            }
        }
        __syncthreads();
        if (tid < 64) {
            float a = s_w[0][tid] + s_w[1][tid] + s_w[2][tid] + s_w[3][tid];
            int L = DEPTH - 1;
            atomicAdd(&stats[L * (NSLOT * 64) + (blockIdx.x & (NSLOT - 1)) * 64 + tid], a);
        }
    }
}

extern "C" void kernel_launch(void* const* d_in, const int* in_sizes, int n_in,
                              void* d_out, int out_size, void* d_ws, size_t ws_size,
                              hipStream_t stream) {
    const float* x   = (const float*)d_in[0];
    const float* W1  = (const float*)d_in[1];
    const float* b1  = (const float*)d_in[2];
    const float* g1  = (const float*)d_in[3];
    const float* be1 = (const float*)d_in[4];
    const float* W2  = (const float*)d_in[5];
    const float* b2  = (const float*)d_in[6];
    const float* g2  = (const float*)d_in[7];
    const float* be2 = (const float*)d_in[8];
    const float* W3  = (const float*)d_in[9];
    const float* b3  = (const float*)d_in[10];
    const float* g3  = (const float*)d_in[11];
    const float* be3 = (const float*)d_in[12];
    const float* W4  = (const float*)d_in[13];
    const float* b4  = (const float*)d_in[14];
    float* out = (float*)d_out;
    int N = in_sizes[0] / 16;

    __bf16* xb   = (__bf16*)d_ws;
    float* stats = (float*)((char*)d_ws + (size_t)N * 16 * 2);

    hipMemsetAsync(stats, 0, 3 * NSLOT * 64 * sizeof(float), stream);

    k_fwd<1><<<NBLK, NTHR, 0, stream>>>(x, xb, W1, b1, g1, be1, W2, b2, g2, be2, W3, b3, g3, be3, W4, b4, stats, out, N);
    k_fwd<2><<<NBLK, NTHR, 0, stream>>>(x, xb, W1, b1, g1, be1, W2, b2, g2, be2, W3, b3, g3, be3, W4, b4, stats, out, N);
    k_fwd<3><<<NBLK, NTHR, 0, stream>>>(x, xb, W1, b1, g1, be1, W2, b2, g2, be2, W3, b3, g3, be3, W4, b4, stats, out, N);
    k_fwd<4><<<NBLK, NTHR, 0, stream>>>(x, xb, W1, b1, g1, be1, W2, b2, g2, be2, W3, b3, g3, be3, W4, b4, stats, out, N);
}